// Round 6
// baseline (539.856 us; speedup 1.0000x reference)
//
#include <hip/hip_runtime.h>

typedef unsigned short u16;
typedef short s16x4 __attribute__((ext_vector_type(4)));
typedef short s16x8 __attribute__((ext_vector_type(8)));
typedef float f32x4 __attribute__((ext_vector_type(4)));

#define DEVFN __device__ __forceinline__

// problem constants
constexpr long AW_OFF  = 4194304;               // attn_output elems (2*2048*1024)
constexpr long PAT_OFF = AW_OFF + 134217728;    // + attn_weights elems (2*16*2048*2048)

DEVFN u16 f2bf(float x) {
  unsigned u = __builtin_bit_cast(unsigned, x);
  unsigned r = (u + 0x7fffu + ((u >> 16) & 1u)) >> 16;   // RNE
  return (u16)r;
}

DEVFN void gld16(const u16* g, u16* l) {
  __builtin_amdgcn_global_load_lds(
      (const __attribute__((address_space(1))) unsigned int*)g,
      (__attribute__((address_space(3))) unsigned int*)l, 16, 0, 0);
}

// ---------------- fp32 -> bf16 elementwise, 3 tensors ----------------
__global__ __launch_bounds__(256) void k_cvt3(const float* __restrict__ a,
                                              const float* __restrict__ b,
                                              const float* __restrict__ c,
                                              u16* __restrict__ out, int n4) {
  int i = blockIdx.x * 256 + threadIdx.x;
  if (i >= n4) return;
  const float* in = (blockIdx.y == 0) ? a : (blockIdx.y == 1) ? b : c;
  float4 v = ((const float4*)in)[i];
  s16x4 o; o[0] = f2bf(v.x); o[1] = f2bf(v.y); o[2] = f2bf(v.z); o[3] = f2bf(v.w);
  ((s16x4*)(out + (long)blockIdx.y * 4194304))[i] = o;
}

// ---------------- pack 3 bias vectors contiguous ----------------
__global__ __launch_bounds__(256) void k_pack3(const float* __restrict__ a,
                                               const float* __restrict__ b,
                                               const float* __restrict__ c,
                                               float* __restrict__ out) {
  int i = blockIdx.x * 256 + threadIdx.x;   // grid 12 -> 3072
  const float* in = (i < 1024) ? a : (i < 2048) ? b : c;
  out[i] = in[i & 1023];
}

// ---------------- merged weight transposes: 7 slices of [1024,1024] ----------------
// z: 0=Wq 1=Wk 2=Wv 3=Wo 4..6=Wa[z-4]; outputs: Wqt(+slice), Wot, Wat(+slice)
__global__ __launch_bounds__(256) void k_trW(const float* __restrict__ Wq,
                                             const float* __restrict__ Wk,
                                             const float* __restrict__ Wv,
                                             const float* __restrict__ Wo,
                                             const float* __restrict__ Wa,
                                             u16* __restrict__ Wqt,
                                             u16* __restrict__ Wot,
                                             u16* __restrict__ Wat) {
  __shared__ u16 tile[32][33];
  const int z = blockIdx.z;
  const float* in;
  u16* outp;
  if (z == 0)      { in = Wq; outp = Wqt; }
  else if (z == 1) { in = Wk; outp = Wqt + 1048576; }
  else if (z == 2) { in = Wv; outp = Wqt + 2097152; }
  else if (z == 3) { in = Wo; outp = Wot; }
  else             { in = Wa + (long)(z - 4) * 1048576; outp = Wat + (long)(z - 4) * 1048576; }
  int k0 = blockIdx.y * 32, n0 = blockIdx.x * 32;
  int tx = threadIdx.x & 31, ty = threadIdx.x >> 5;
#pragma unroll
  for (int i = 0; i < 4; ++i)
    tile[ty + i * 8][tx] = f2bf(in[(long)(k0 + ty + i * 8) * 1024 + (n0 + tx)]);
  __syncthreads();
#pragma unroll
  for (int i = 0; i < 4; ++i)
    outp[(long)(n0 + ty + i * 8) * 1024 + (k0 + tx)] = tile[tx][ty + i * 8];
}

// ---------------- tiled transpose: out[n][k] = bf16(in[k][n]) ----------------
template <bool IN_F32>
__global__ __launch_bounds__(256) void k_tr(const void* __restrict__ inv,
                                            u16* __restrict__ out,
                                            long ldin, long ldout,
                                            long inz1, long inz2, long outz, int zdiv) {
  __shared__ u16 tile[32][33];
  int z = blockIdx.z;
  long ioff = (long)(z / zdiv) * inz1 + (long)(z % zdiv) * inz2;
  int k0 = blockIdx.y * 32, n0 = blockIdx.x * 32;
  int tx = threadIdx.x, ty = threadIdx.y;
#pragma unroll
  for (int i = 0; i < 4; ++i) {
    long k = k0 + ty + i * 8, n = n0 + tx;
    u16 v;
    if constexpr (IN_F32) v = f2bf(((const float*)inv)[ioff + k * ldin + n]);
    else                  v = ((const u16*)inv)[ioff + k * ldin + n];
    tile[ty + i * 8][tx] = v;
  }
  __syncthreads();
  long ooff = (long)z * outz;
#pragma unroll
  for (int i = 0; i < 4; ++i) {
    long n = n0 + ty + i * 8, k = k0 + tx;
    out[ooff + n * ldout + k] = tile[tx][ty + i * 8];
  }
}

// ---------------- 128x128 NT GEMM (kept for K=64 weights writer) ----------------
// EPI 0: v = alpha*acc + bias[z2][col];  EPI 1: v = exp(alpha*acc) * rinv[z][row]
template <typename OutT, int EPI>
__global__ __launch_bounds__(256) void k_gemm_nt(
    const u16* __restrict__ Ap, const u16* __restrict__ Bp, OutT* __restrict__ Cp,
    const float* __restrict__ bias, const float* __restrict__ rinv, float alpha, int K,
    long lda, long ldb, long ldc,
    long saz1, long saz2, long sbz1, long sbz2, long scz1, long scz2,
    long sbias, int zdiv) {
  __shared__ __align__(16) u16 At[128][64];
  __shared__ __align__(16) u16 Bt[128][64];
  const int tid = threadIdx.x, lane = tid & 63, wid = tid >> 6;
  const int wm = wid >> 1, wn = wid & 1;

  const int gx = gridDim.x, gy = gridDim.y;
  int id = (blockIdx.z * gy + blockIdx.y) * gx + blockIdx.x;
  const int nb = gx * gy * (int)gridDim.z;
  if ((nb & 7) == 0) id = (id & 7) * (nb >> 3) + (id >> 3);
  const int bxi = id % gx, byi = (id / gx) % gy, bzi = id / (gx * gy);

  const int z = bzi, z1 = z / zdiv, z2 = z % zdiv;
  const u16* Ab = Ap + (long)z1 * saz1 + (long)z2 * saz2;
  const u16* Bb = Bp + (long)z1 * sbz1 + (long)z2 * sbz2;
  OutT* C = Cp + (long)z1 * scz1 + (long)z2 * scz2;
  const float* bv = bias ? bias + (long)z2 * sbias : nullptr;
  const int row0 = byi * 128, col0 = bxi * 128;
  const int lk = lane & 15, g = lane >> 4;

  f32x4 acc[4][4] = {};

  for (int k0 = 0; k0 < K; k0 += 64) {
#pragma unroll
    for (int it = 0; it < 4; ++it) {
      const int u = it * 256 + tid;
      const int r = u >> 3, p = u & 7;
      const int cg = (p ^ (r & 7)) * 8;
      gld16(Ab + (long)(row0 + r) * lda + (k0 + cg), &At[r][p * 8]);
      gld16(Bb + (long)(col0 + r) * ldb + (k0 + cg), &Bt[r][p * 8]);
    }
    __syncthreads();
#pragma unroll
    for (int kk = 0; kk < 2; ++kk) {
      s16x8 af[4], bf[4];
#pragma unroll
      for (int m = 0; m < 4; ++m)
        af[m] = *(const s16x8*)&At[wm * 64 + m * 16 + lk][((kk * 4 + g) ^ (lk & 7)) * 8];
#pragma unroll
      for (int n = 0; n < 4; ++n)
        bf[n] = *(const s16x8*)&Bt[wn * 64 + n * 16 + lk][((kk * 4 + g) ^ (lk & 7)) * 8];
#pragma unroll
      for (int m = 0; m < 4; ++m)
#pragma unroll
        for (int n = 0; n < 4; ++n)
          acc[m][n] = __builtin_amdgcn_mfma_f32_16x16x32_bf16(af[m], bf[n], acc[m][n], 0, 0, 0);
    }
    __syncthreads();
  }

  const float* rz = (EPI == 1) ? rinv + (long)z * 2048 : nullptr;
#pragma unroll
  for (int m = 0; m < 4; ++m) {
    const int grow = row0 + wm * 64 + m * 16 + g * 4;
#pragma unroll
    for (int r = 0; r < 4; ++r) {
      float iv = 0.0f;
      if constexpr (EPI == 1) iv = rz[grow + r];
#pragma unroll
      for (int n = 0; n < 4; ++n) {
        const int gcol = col0 + wn * 64 + n * 16 + lk;
        float v;
        if constexpr (EPI == 1) v = __expf(alpha * acc[m][n][r]) * iv;
        else                    v = alpha * acc[m][n][r] + (bv ? bv[gcol] : 0.0f);
        if constexpr (sizeof(OutT) == 2) C[(long)(grow + r) * ldc + gcol] = f2bf(v);
        else                             C[(long)(grow + r) * ldc + gcol] = v;
      }
    }
  }
}

// ---------------- 256x256 pipelined NT GEMM (K multiple of 64, NT>=2) ----------------
// 8 waves (2M x 4N), BK=64, double-buffered dynamic LDS (128 KiB), counted vmcnt
// across raw s_barriers (T3+T4), T2 XOR-swizzle staging/reads as in k_gemm_nt.
template <typename OutT, int EPI>
__global__ __launch_bounds__(512, 1) void k_gemm8(
    const u16* __restrict__ Ap, const u16* __restrict__ Bp, OutT* __restrict__ Cp,
    const float* __restrict__ bias, const float* __restrict__ rinv, float alpha, int K,
    long lda, long ldb, long ldc,
    long saz1, long saz2, long sbz1, long sbz2, long scz1, long scz2,
    long sbias, int zdiv) {
  extern __shared__ __align__(16) u16 dyn[];
  u16* At = dyn;               // [2][256][64]
  u16* Bt = dyn + 32768;       // [2][256][64]
  const int tid = threadIdx.x, lane = tid & 63, wid = tid >> 6;
  const int wm = wid >> 2, wn = wid & 3;

  const int gx = gridDim.x, gy = gridDim.y;
  int id = (blockIdx.z * gy + blockIdx.y) * gx + blockIdx.x;
  const int nb = gx * gy * (int)gridDim.z;
  if ((nb & 7) == 0) id = (id & 7) * (nb >> 3) + (id >> 3);
  const int bxi = id % gx, byi = (id / gx) % gy, bzi = id / (gx * gy);

  const int z = bzi, z1 = z / zdiv, z2 = z % zdiv;
  const u16* Ab = Ap + (long)z1 * saz1 + (long)z2 * saz2;
  const u16* Bb = Bp + (long)z1 * sbz1 + (long)z2 * sbz2;
  OutT* C = Cp + (long)z1 * scz1 + (long)z2 * scz2;
  const float* bv = bias ? bias + (long)z2 * sbias : nullptr;
  const int row0 = byi * 256, col0 = bxi * 256;
  const int lk = lane & 15, g = lane >> 4;

  f32x4 acc[8][4] = {};
  const int NT = K >> 6;

  auto STAGE = [&](int t, int b) {
    const int k0 = t << 6;
#pragma unroll
    for (int it = 0; it < 4; ++it) {
      const int u = it * 512 + tid;
      const int r = u >> 3, p = u & 7;
      const int cg = (p ^ (r & 7)) * 8;
      gld16(Ab + (long)(row0 + r) * lda + (k0 + cg), At + b * 16384 + r * 64 + p * 8);
      gld16(Bb + (long)(col0 + r) * ldb + (k0 + cg), Bt + b * 16384 + r * 64 + p * 8);
    }
  };

  STAGE(0, 0);
  STAGE(1, 1);
  for (int t = 0; t < NT; ++t) {
    // tile t resident for THIS wave; every wave does the same, then barrier =>
    // tile t fully in LDS. Keeps tile t+1's 8 loads in flight (counted vmcnt).
    if (t + 1 < NT) asm volatile("s_waitcnt vmcnt(8)" ::: "memory");
    else            asm volatile("s_waitcnt vmcnt(0)" ::: "memory");
    __builtin_amdgcn_sched_barrier(0);
    __builtin_amdgcn_s_barrier();
    __builtin_amdgcn_sched_barrier(0);
    const u16* Ax = At + (t & 1) * 16384;
    const u16* Bx = Bt + (t & 1) * 16384;
#pragma unroll
    for (int kk = 0; kk < 2; ++kk) {
      s16x8 af[8], bf[4];
#pragma unroll
      for (int m = 0; m < 8; ++m)
        af[m] = *(const s16x8*)(Ax + (wm * 128 + m * 16 + lk) * 64 + ((kk * 4 + g) ^ (lk & 7)) * 8);
#pragma unroll
      for (int n = 0; n < 4; ++n)
        bf[n] = *(const s16x8*)(Bx + (wn * 64 + n * 16 + lk) * 64 + ((kk * 4 + g) ^ (lk & 7)) * 8);
#pragma unroll
      for (int m = 0; m < 8; ++m)
#pragma unroll
        for (int n = 0; n < 4; ++n)
          acc[m][n] = __builtin_amdgcn_mfma_f32_16x16x32_bf16(af[m], bf[n], acc[m][n], 0, 0, 0);
    }
    // MFMA consumption forced lgkm completion of all frag reads before here.
    __builtin_amdgcn_sched_barrier(0);
    __builtin_amdgcn_s_barrier();
    __builtin_amdgcn_sched_barrier(0);
    if (t + 2 < NT) STAGE(t + 2, t & 1);
  }

  const float* rz = (EPI == 1) ? rinv + (long)z * 2048 : nullptr;
#pragma unroll
  for (int m = 0; m < 8; ++m) {
    const int grow = row0 + wm * 128 + m * 16 + g * 4;
#pragma unroll
    for (int r = 0; r < 4; ++r) {
      float iv = 0.0f;
      if constexpr (EPI == 1) iv = rz[grow + r];
#pragma unroll
      for (int n = 0; n < 4; ++n) {
        const int gcol = col0 + wn * 64 + n * 16 + lk;
        float v;
        if constexpr (EPI == 1) v = __expf(alpha * acc[m][n][r]) * iv;
        else                    v = alpha * acc[m][n][r] + (bv ? bv[gcol] : 0.0f);
        if constexpr (sizeof(OutT) == 2) C[(long)(grow + r) * ldc + gcol] = f2bf(v);
        else                             C[(long)(grow + r) * ldc + gcol] = v;
      }
    }
  }
}

// ---------------- flash attention: ctx[b,s,h*64+d], rinv[bh,q] = 1/sum(exp) ----------------
__global__ __launch_bounds__(256) void k_flash(
    const u16* __restrict__ qp, const u16* __restrict__ kp, const u16* __restrict__ vt,
    u16* __restrict__ ctx, float* __restrict__ rinv) {
  __shared__ __align__(16) char lds[49152];
  u16* Qt = (u16*)lds;            // [128][64]
  u16* Kt = (u16*)(lds + 16384);  // [128][64]
  u16* Vl = (u16*)(lds + 32768);  // [64][128]
  const int tid = threadIdx.x, lane = tid & 63, wid = tid >> 6;
  const int wk = wid >> 1, wq = wid & 1;

  const int gx = gridDim.x;
  int id = blockIdx.y * gx + blockIdx.x;
  const int nb = gx * (int)gridDim.y;
  if ((nb & 7) == 0) id = (id & 7) * (nb >> 3) + (id >> 3);
  const int bh = id / gx, q0 = (id % gx) * 128;

  const long qkbase = (long)(bh >> 4) * 2097152 + (long)(bh & 15) * 64;
  const long vbase = (long)bh * 131072;
  const int lk = lane & 15, g = lane >> 4;
  const int sp = lane & 7;
  const int sr = lane >> 3;

#pragma unroll
  for (int i = 0; i < 4; ++i) {
    const int rr = (wid * 4 + i) * 8 + sr;
    gld16(qp + qkbase + (long)(q0 + rr) * 1024 + ((sp ^ (rr & 7)) * 8), Qt + rr * 64 + sp * 8);
  }
  __syncthreads();

  s16x8 qf[2][4];
#pragma unroll
  for (int kk = 0; kk < 2; ++kk) {
#pragma unroll
    for (int nq = 0; nq < 4; ++nq)
      qf[kk][nq] = *(const s16x8*)(Qt + (wq * 64 + nq * 16 + lk) * 64 + ((kk * 4 + g) ^ (lk & 7)) * 8);
  }

  f32x4 cacc[4][4] = {};
  float rs[4] = {0.f, 0.f, 0.f, 0.f};

  for (int t = 0; t < 16; ++t) {
    const int kb = t * 128;
#pragma unroll
    for (int i = 0; i < 4; ++i) {
      const int rr = (wid * 4 + i) * 8 + sr;
      gld16(kp + qkbase + (long)(kb + rr) * 1024 + ((sp ^ (rr & 7)) * 8), Kt + rr * 64 + sp * 8);
      const int dd = (wid * 4 + i) * 4 + g;
      const int pv = lane & 15;
      const int cv = (pv & 8) | ((pv ^ dd) & 7);
      gld16(vt + vbase + (long)dd * 2048 + (kb + cv * 8), Vl + dd * 128 + pv * 8);
    }
    __syncthreads();

    f32x4 st[4][4] = {};
#pragma unroll
    for (int kk = 0; kk < 2; ++kk) {
      s16x8 af[4];
#pragma unroll
      for (int mk = 0; mk < 4; ++mk)
        af[mk] = *(const s16x8*)(Kt + (wk * 64 + mk * 16 + lk) * 64 + ((kk * 4 + g) ^ (lk & 7)) * 8);
#pragma unroll
      for (int mk = 0; mk < 4; ++mk)
#pragma unroll
        for (int nq = 0; nq < 4; ++nq)
          st[mk][nq] = __builtin_amdgcn_mfma_f32_16x16x32_bf16(af[mk], qf[kk][nq], st[mk][nq], 0, 0, 0);
    }
#pragma unroll
    for (int mk = 0; mk < 4; ++mk)
#pragma unroll
      for (int nq = 0; nq < 4; ++nq)
#pragma unroll
        for (int j = 0; j < 4; ++j) {
          const float p = __expf(st[mk][nq][j] * 0.125f);
          st[mk][nq][j] = p;
          rs[nq] += p;
        }
#pragma unroll
    for (int ks = 0; ks < 2; ++ks) {
      s16x8 pb[4];
#pragma unroll
      for (int nq = 0; nq < 4; ++nq) {
        s16x8 b;
#pragma unroll
        for (int j = 0; j < 4; ++j) {
          b[j]     = (short)f2bf(st[2 * ks][nq][j]);
          b[4 + j] = (short)f2bf(st[2 * ks + 1][nq][j]);
        }
        pb[nq] = b;
      }
#pragma unroll
      for (int md = 0; md < 4; ++md) {
        const int rowv = md * 16 + lk;
        const int u0 = ks * 4 + (g >> 1);
        const int p0 = wk * 8 + ((u0 ^ (rowv & 7)) & 7);
        const int p2 = wk * 8 + (((u0 + 2) ^ (rowv & 7)) & 7);
        const u16* vb0 = Vl + rowv * 128 + p0 * 8 + (g & 1) * 4;
        const u16* vb2 = Vl + rowv * 128 + p2 * 8 + (g & 1) * 4;
        s16x4 lo = *(const s16x4*)vb0;
        s16x4 hi = *(const s16x4*)vb2;
        s16x8 vf;
        vf[0] = lo[0]; vf[1] = lo[1]; vf[2] = lo[2]; vf[3] = lo[3];
        vf[4] = hi[0]; vf[5] = hi[1]; vf[6] = hi[2]; vf[7] = hi[3];
#pragma unroll
        for (int nq = 0; nq < 4; ++nq)
          cacc[md][nq] = __builtin_amdgcn_mfma_f32_16x16x32_bf16(vf, pb[nq], cacc[md][nq], 0, 0, 0);
      }
    }
    __syncthreads();
  }

#pragma unroll
  for (int nq = 0; nq < 4; ++nq) {
    rs[nq] += __shfl_xor(rs[nq], 16, 64);
    rs[nq] += __shfl_xor(rs[nq], 32, 64);
  }
  float* ctxl = (float*)lds;            // [64][129]
  float* rsl  = (float*)(lds + 33024);  // [128]
  if (wk == 1) {
#pragma unroll
    for (int md = 0; md < 4; ++md)
#pragma unroll
      for (int nq = 0; nq < 4; ++nq)
#pragma unroll
        for (int r = 0; r < 4; ++r)
          ctxl[(md * 16 + g * 4 + r) * 129 + wq * 64 + nq * 16 + lk] = cacc[md][nq][r];
    if (lane < 16)
#pragma unroll
      for (int nq = 0; nq < 4; ++nq) rsl[wq * 64 + nq * 16 + lane] = rs[nq];
  }
  __syncthreads();
  if (wk == 0) {
#pragma unroll
    for (int md = 0; md < 4; ++md)
#pragma unroll
      for (int nq = 0; nq < 4; ++nq)
#pragma unroll
        for (int r = 0; r < 4; ++r) {
          const int idx = (md * 16 + g * 4 + r) * 129 + wq * 64 + nq * 16 + lk;
          ctxl[idx] += cacc[md][nq][r];
        }
    if (lane < 16)
#pragma unroll
      for (int nq = 0; nq < 4; ++nq) {
        const int qi = wq * 64 + nq * 16 + lane;
        const float inv = 1.0f / (rsl[qi] + rs[nq]);
        rsl[qi] = inv;
        rinv[(long)bh * 2048 + q0 + qi] = inv;
      }
  }
  __syncthreads();
  const int qr = tid >> 1, half = tid & 1;
  const float inv = rsl[qr];
  u16* dst = ctx + (long)(bh >> 4) * 2097152 + (long)(q0 + qr) * 1024 + (long)(bh & 15) * 64 + half * 32;
#pragma unroll
  for (int c = 0; c < 4; ++c) {
    s16x8 o;
#pragma unroll
    for (int j = 0; j < 8; ++j) {
      const int d = half * 32 + c * 8 + j;
      o[j] = (short)f2bf(ctxl[d * 129 + qr] * inv);
    }
    ((s16x8*)dst)[c] = o;
  }
}

// ---------------- in-place row softmax, rows of 2048 fp32 ----------------
__global__ __launch_bounds__(256) void k_softmax(float* __restrict__ base) {
  float* p = base + (long)blockIdx.x * 2048;
  const int t = threadIdx.x;
  float4 v0 = ((const float4*)p)[t];
  float4 v1 = ((const float4*)p)[t + 256];
  float m = fmaxf(fmaxf(fmaxf(v0.x, v0.y), fmaxf(v0.z, v0.w)),
                  fmaxf(fmaxf(v1.x, v1.y), fmaxf(v1.z, v1.w)));
#pragma unroll
  for (int i = 32; i >= 1; i >>= 1) m = fmaxf(m, __shfl_xor(m, i, 64));
  __shared__ float sm[4], ss[4];
  if ((t & 63) == 0) sm[t >> 6] = m;
  __syncthreads();
  m = fmaxf(fmaxf(sm[0], sm[1]), fmaxf(sm[2], sm[3]));
  float4 e0, e1;
  e0.x = __expf(v0.x - m); e0.y = __expf(v0.y - m); e0.z = __expf(v0.z - m); e0.w = __expf(v0.w - m);
  e1.x = __expf(v1.x - m); e1.y = __expf(v1.y - m); e1.z = __expf(v1.z - m); e1.w = __expf(v1.w - m);
  float s = (e0.x + e0.y + e0.z + e0.w) + (e1.x + e1.y + e1.z + e1.w);
#pragma unroll
  for (int i = 32; i >= 1; i >>= 1) s += __shfl_xor(s, i, 64);
  if ((t & 63) == 0) ss[t >> 6] = s;
  __syncthreads();
  s = ss[0] + ss[1] + ss[2] + ss[3];
  float inv = 1.0f / s;
  e0.x *= inv; e0.y *= inv; e0.z *= inv; e0.w *= inv;
  e1.x *= inv; e1.y *= inv; e1.z *= inv; e1.w *= inv;
  ((float4*)p)[t] = e0;
  ((float4*)p)[t + 256] = e1;
}

// ---------------- launch ----------------
extern "C" void kernel_launch(void* const* d_in, const int* in_sizes, int n_in,
                              void* d_out, int out_size, void* d_ws, size_t ws_size,
                              hipStream_t stream) {
  const float* query = (const float*)d_in[0];
  const float* key   = (const float*)d_in[1];
  const float* value = (const float*)d_in[2];
  const float* Wq = (const float*)d_in[3];
  const float* bq = (const float*)d_in[4];
  const float* Wk = (const float*)d_in[5];
  const float* bk = (const float*)d_in[6];
  const float* Wv = (const float*)d_in[7];
  const float* bv = (const float*)d_in[8];
  const float* Wo = (const float*)d_in[9];
  const float* bo = (const float*)d_in[10];
  const float* Wa = (const float*)d_in[11];
  const float* ba = (const float*)d_in[12];
  float* out = (float*)d_out;
  char* ws = (char*)d_ws;

  // workspace layout (bytes)
  u16* qb  = (u16*)(ws + 0);           // [3][4096,1024] bf16 q,k,v (contiguous)
  u16* Wqt = (u16*)(ws + 25165824);    // [3][1024,1024] Wq^T,Wk^T,Wv^T bf16 (contig; reused as rinv)
  u16* Wot = (u16*)(ws + 31457280);
  u16* Wat = (u16*)(ws + 33554432);    // [3,1024,1024]
  u16* qp  = (u16*)(ws + 39845888);    // [3][4096,1024] projected q,k,v (contiguous)
  u16* kp  = (u16*)(ws + 48234496);
  u16* vp  = (u16*)(ws + 56623104);
  u16* vt  = (u16*)(ws + 65011712);    // [B,H,64,2048] V^T per head
  u16* ctx = (u16*)(ws + 73400320);    // [4096,1024]
  u16* qa  = (u16*)(ws + 81788928);    // [2][3][4096,1024] aspect q then aspect k (contiguous)
  float* rinv  = (float*)(ws + 25165824);   // [32,2048] (overwrites Wqt after proj)
  float* pbias = (float*)(ws + 132120576);  // [3,1024] packed bq,bk,bv

  // allow 128 KiB dynamic LDS for the pipelined GEMM (idempotent)
  hipFuncSetAttribute((const void*)k_gemm8<u16, 0>,
                      hipFuncAttributeMaxDynamicSharedMemorySize, 131072);
  hipFuncSetAttribute((const void*)k_gemm8<float, 0>,
                      hipFuncAttributeMaxDynamicSharedMemorySize, 131072);

  dim3 b256(256), b512(512);
  dim3 trb(32, 8);

  // bf16 conversions of q,k,v activations (one launch) + bias pack
  k_cvt3<<<dim3(4096, 3), b256, 0, stream>>>(query, key, value, qb, 1048576);
  k_pack3<<<12, b256, 0, stream>>>(bq, bk, bv, pbias);

  // all weight transposes in ONE launch (z = 0..6)
  k_trW<<<dim3(32, 32, 7), b256, 0, stream>>>(Wq, Wk, Wv, Wo, Wa, Wqt, Wot, Wat);

  // Q/K/V projections in ONE launch (z = 0,1,2) -> qp,kp,vp
  k_gemm8<u16, 0><<<dim3(4, 16, 3), b512, 131072, stream>>>(
      qb, Wqt, qp, pbias, nullptr, 1.0f, 1024, 1024, 1024, 1024,
      0, 4194304, 0, 1048576, 0, 4194304, 1024, 3);

  // aspect projections of q and k in ONE launch (z1 = q/k, z2 = aspect)
  k_gemm8<u16, 0><<<dim3(4, 16, 6), b512, 131072, stream>>>(
      qb, Wat, qa, ba, nullptr, 1.0f, 1024, 1024, 1024, 1024,
      4194304, 0, 0, 1048576, 12582912, 4194304, 1024, 3);

  // per-head V^T: vt[b,h][d][s]  (z = b*16+h)
  k_tr<false><<<dim3(2, 64, 32), trb, 0, stream>>>(
      vp, vt, 1024, 2048, 2097152, 64, 131072, 16);

  // flash attention: ctx (bf16) + rinv
  k_flash<<<dim3(16, 32), b256, 0, stream>>>(qp, kp, vt, ctx, rinv);

  // attn_weights = exp(QK^T * scale) * rinv  -> d_out (single write pass, K=64)
  k_gemm_nt<float, 1><<<dim3(16, 16, 32), b256, 0, stream>>>(
      qp, kp, out + AW_OFF, nullptr, rinv, 0.125f, 64, 1024, 1024, 2048,
      2097152, 64, 2097152, 64, 67108864, 4194304, 0, 16);

  // full-dim pattern logits -> d_out patterns region (z = a*2+b)
  k_gemm8<float, 0><<<dim3(8, 8, 6), b512, 131072, stream>>>(
      qa, qa + 12582912, out + PAT_OFF, nullptr, nullptr, 0.125f, 1024, 1024, 1024, 2048,
      0, 2097152, 0, 2097152, 0, 4194304, 0, 6);

  // softmax over patterns only (3*B*S = 12288 rows of 2048)
  k_softmax<<<12288, b256, 0, stream>>>(out + PAT_OFF);

  // output projection -> d_out attn_output
  k_gemm8<float, 0><<<dim3(4, 16, 1), b512, 131072, stream>>>(
      ctx, Wot, out, bo, nullptr, 1.0f, 1024, 1024, 1024, 1024,
      0, 0, 0, 0, 0, 0, 0, 1);
}